// Round 1
// baseline (144.294 us; speedup 1.0000x reference)
//
#include <hip/hip_runtime.h>

typedef __attribute__((ext_vector_type(8))) short bf16x8;   // 8 bf16 in 4 VGPRs
typedef __attribute__((ext_vector_type(4))) float f32x4;

#define GLDS16(SRC, DST) __builtin_amdgcn_global_load_lds( \
    (const __attribute__((address_space(1))) void*)(SRC),  \
    (__attribute__((address_space(3))) void*)(DST), 16, 0, 0)

__device__ __forceinline__ unsigned short f2bf(float f) {
  unsigned int u = __float_as_uint(f);
  u += 0x7FFFu + ((u >> 16) & 1u);       // RNE
  return (unsigned short)(u >> 16);
}

// ---------------- fp32 -> bf16 convert (optionally scaled) ----------------
__global__ void cvt_f32_bf16(const float* __restrict__ in, unsigned short* __restrict__ out,
                             int n4, float scale) {
  int i = blockIdx.x * blockDim.x + threadIdx.x;
  if (i >= n4) return;
  float4 v = ((const float4*)in)[i];
  ushort4 o;
  o.x = f2bf(v.x * scale); o.y = f2bf(v.y * scale);
  o.z = f2bf(v.z * scale); o.w = f2bf(v.w * scale);
  ((ushort4*)out)[i] = o;
}

// ---------------- concat biases (Q bias pre-scaled by 1/8) ----------------
__global__ void build_bcat(const float* __restrict__ bq, const float* __restrict__ bk,
                           const float* __restrict__ bv, float* __restrict__ bcat) {
  int i = blockIdx.x * blockDim.x + threadIdx.x;
  if (i >= 3072) return;
  float v = (i < 1024) ? bq[i] * 0.125f : (i < 2048 ? bk[i - 1024] : bv[i - 2048]);
  bcat[i] = v;
}

// ---------------- C = A * B^T + bias ; A[M,K] bf16, B[N,K] bf16 -----------
// m97 structure: 128x128 tile, BK=32, 4 waves (2x2), 16x16x32 MFMA,
// double-buffered LDS fed by global_load_lds width=16.
template <typename OutT>
__global__ __launch_bounds__(256) void gemm_bt(
    const unsigned short* __restrict__ A, const unsigned short* __restrict__ B,
    const float* __restrict__ bias, OutT* __restrict__ C,
    int M, int N, int K, int lda, int ldb, int ldc)
{
  __shared__ __align__(16) unsigned short As[2][128 * 32];
  __shared__ __align__(16) unsigned short Bs[2][128 * 32];
  const int t = threadIdx.x;
  const int lane = t & 63;
  const int w = t >> 6;
  const int wm = w >> 1, wn = w & 1;
  const int lr = lane & 15, lk = lane >> 4;
  const int tm = blockIdx.y * 128, tn = blockIdx.x * 128;

  f32x4 acc[4][4];
#pragma unroll
  for (int m = 0; m < 4; ++m)
#pragma unroll
    for (int n = 0; n < 4; ++n) acc[m][n] = (f32x4){0.f, 0.f, 0.f, 0.f};

  // staging geometry: thread t owns LDS elems t*8 (instr0) and (256+t)*8 (instr1)
  const int ra0 = t >> 2;            // row = (t*8)/32
  const int ka0 = (t & 3) << 3;      // k within tile
  const int ra1 = 64 + (t >> 2);
  const int lds0 = (t & 192) * 8;            // wave-uniform base (elems)
  const int lds1 = (256 + (t & 192)) * 8;

  const int NT = K >> 5;
  GLDS16(A + (size_t)(tm + ra0) * lda + ka0, &As[0][lds0]);
  GLDS16(A + (size_t)(tm + ra1) * lda + ka0, &As[0][lds1]);
  GLDS16(B + (size_t)(tn + ra0) * ldb + ka0, &Bs[0][lds0]);
  GLDS16(B + (size_t)(tn + ra1) * ldb + ka0, &Bs[0][lds1]);
  __syncthreads();

  for (int kt = 0; kt < NT; ++kt) {
    const int cur = kt & 1, nxt = cur ^ 1;
    if (kt + 1 < NT) {
      const int k0 = (kt + 1) << 5;
      GLDS16(A + (size_t)(tm + ra0) * lda + k0 + ka0, &As[nxt][lds0]);
      GLDS16(A + (size_t)(tm + ra1) * lda + k0 + ka0, &As[nxt][lds1]);
      GLDS16(B + (size_t)(tn + ra0) * ldb + k0 + ka0, &Bs[nxt][lds0]);
      GLDS16(B + (size_t)(tn + ra1) * ldb + k0 + ka0, &Bs[nxt][lds1]);
    }
    bf16x8 af[4], bfv[4];
#pragma unroll
    for (int m = 0; m < 4; ++m)
      af[m] = *(const bf16x8*)&As[cur][(wm * 64 + m * 16 + lr) * 32 + lk * 8];
#pragma unroll
    for (int n = 0; n < 4; ++n)
      bfv[n] = *(const bf16x8*)&Bs[cur][(wn * 64 + n * 16 + lr) * 32 + lk * 8];
#pragma unroll
    for (int m = 0; m < 4; ++m)
#pragma unroll
      for (int n = 0; n < 4; ++n)
        acc[m][n] = __builtin_amdgcn_mfma_f32_16x16x32_bf16(af[m], bfv[n], acc[m][n], 0, 0, 0);
    __syncthreads();
  }

  // epilogue: C/D layout col=lane&15, row=(lane>>4)*4+reg  [m89]
#pragma unroll
  for (int m = 0; m < 4; ++m) {
    const int row0 = tm + wm * 64 + m * 16 + lk * 4;
#pragma unroll
    for (int n = 0; n < 4; ++n) {
      const int col = tn + wn * 64 + n * 16 + lr;
      const float bb = bias ? bias[col] : 0.f;
#pragma unroll
      for (int r = 0; r < 4; ++r) {
        float v = acc[m][n][r] + bb;
        if constexpr (sizeof(OutT) == 2) {
          ((unsigned short*)C)[(size_t)(row0 + r) * ldc + col] = f2bf(v);
        } else {
          ((float*)C)[(size_t)(row0 + r) * ldc + col] = v;
        }
      }
    }
  }
}

// ---------------- causal flash attention -----------------------------------
// QKV: [2048][3072] bf16 (Q|K|V per head-column blocks), Q pre-scaled by 1/8.
// Block: 4 waves, one 64-row q-tile of one head; wave w owns rows q0+w*16..+15.
// K LDS: [64 kv][64 d] with 16B-slot XOR swizzle key (row&7), staged via
// global_load_lds with pre-swizzled SOURCE (rule #21).
// V LDS: transposed [64 d][64 kv], slot-swizzle key (d^(d>>3))&7 so both the
// transpose writes (2-way) and b128 reads (2-way) are conflict-free-ish.
__global__ __launch_bounds__(256) void attn_fwd(const unsigned short* __restrict__ QKV,
                                                unsigned short* __restrict__ ctx)
{
  __shared__ __align__(16) unsigned short Ks[64 * 64];
  __shared__ __align__(16) unsigned short Vt[64 * 64];
  __shared__ __align__(16) unsigned short Pl[4][16 * 72];   // per-wave P, stride 72

  const int t = threadIdx.x;
  const int lane = t & 63, w = t >> 6;
  const int lr = lane & 15, lk = lane >> 4;
  const int h = blockIdx.y;
  const int qt = (int)gridDim.x - 1 - (int)blockIdx.x;   // heavy tiles first
  const int q0 = qt * 64;
  const size_t ldq = 3072;

  // Q A-frags: lane holds Q[q0+w*16+lr][slice*32 + lk*8 + i]
  const unsigned short* qbase = QKV + (size_t)(q0 + w * 16 + lr) * ldq + h * 64;
  const bf16x8 aq0 = *(const bf16x8*)(qbase + lk * 8);
  const bf16x8 aq1 = *(const bf16x8*)(qbase + 32 + lk * 8);

  f32x4 acc[4];
#pragma unroll
  for (int d = 0; d < 4; ++d) acc[d] = (f32x4){0.f, 0.f, 0.f, 0.f};
  float mrun[4], lrun[4];
#pragma unroll
  for (int r = 0; r < 4; ++r) { mrun[r] = -__builtin_inff(); lrun[r] = 0.f; }

  // staging geometry: thread t covers elems t*8 / (256+t)*8 of a 64x64 tile
  const int srow0 = t >> 3;           // kv row 0..31
  const int srow1 = 32 + (t >> 3);    // kv row 32..63
  const int sslot = t & 7;            // 16B slot within 128B row

  const unsigned short* kbase = QKV + 1024 + h * 64;
  const unsigned short* vbase = QKV + 2048 + h * 64;

  const int ntiles = qt + 1;
  for (int kt = 0; kt < ntiles; ++kt) {
    const int kv0 = kt * 64;
    __syncthreads();   // prior tile fully consumed before overwrite
    // --- stage K (linear LDS dest, inverse-swizzled global source) ---
    {
      const int c0 = (sslot ^ (srow0 & 7)) << 3;
      const int c1 = (sslot ^ (srow1 & 7)) << 3;
      GLDS16(kbase + (size_t)(kv0 + srow0) * ldq + c0, &Ks[(t & 192) * 8]);
      GLDS16(kbase + (size_t)(kv0 + srow1) * ldq + c1, &Ks[(256 + (t & 192)) * 8]);
    }
    // --- stage V transposed with slot swizzle ---
    {
      const bf16x8 v0 = *(const bf16x8*)(vbase + (size_t)(kv0 + srow0) * ldq + (sslot << 3));
      const bf16x8 v1 = *(const bf16x8*)(vbase + (size_t)(kv0 + srow1) * ldq + (sslot << 3));
      const int d0 = sslot << 3;
#pragma unroll
      for (int j = 0; j < 8; ++j) {
        const int d = d0 + j;
        const int key = (d ^ (d >> 3)) & 7;
        Vt[d * 64 + (((srow0 >> 3) ^ key) << 3) + (srow0 & 7)] = (unsigned short)v0[j];
        Vt[d * 64 + (((srow1 >> 3) ^ key) << 3) + (srow1 & 7)] = (unsigned short)v1[j];
      }
    }
    __syncthreads();   // staging visible (drains vmcnt+lgkm)

    // --- S = Q K^T : 4 kv-subtiles x 2 d-slices ---
    f32x4 sacc[4];
#pragma unroll
    for (int sub = 0; sub < 4; ++sub) {
      const int krow = sub * 16 + lr;
      const int sw = krow & 7;
      const bf16x8 b0 = *(const bf16x8*)&Ks[krow * 64 + ((lk ^ sw) << 3)];
      const bf16x8 b1 = *(const bf16x8*)&Ks[krow * 64 + (((4 + lk) ^ sw) << 3)];
      f32x4 s = (f32x4){0.f, 0.f, 0.f, 0.f};
      s = __builtin_amdgcn_mfma_f32_16x16x32_bf16(aq0, b0, s, 0, 0, 0);
      s = __builtin_amdgcn_mfma_f32_16x16x32_bf16(aq1, b1, s, 0, 0, 0);
      sacc[sub] = s;
    }

    // --- causal mask (diagonal tile only) ---
    if (kt == ntiles - 1) {
      const int qb = w * 16 + lk * 4;   // local q base; kv local = sub*16+lr
#pragma unroll
      for (int sub = 0; sub < 4; ++sub) {
        const int kvl = sub * 16 + lr;
#pragma unroll
        for (int r = 0; r < 4; ++r)
          if (kvl > qb + r) sacc[sub][r] = -__builtin_inff();
      }
    }

    // --- online softmax (rows live in lanes lk*..; reduce over 16 lanes) ---
    float mnew[4];
#pragma unroll
    for (int r = 0; r < 4; ++r) {
      float pm = fmaxf(fmaxf(sacc[0][r], sacc[1][r]), fmaxf(sacc[2][r], sacc[3][r]));
#pragma unroll
      for (int off = 1; off < 16; off <<= 1) pm = fmaxf(pm, __shfl_xor(pm, off, 64));
      mnew[r] = fmaxf(mrun[r], pm);
    }
    float rs[4];
#pragma unroll
    for (int r = 0; r < 4; ++r) {
      const float sc = __expf(mrun[r] - mnew[r]);   // 0 on first tile
      lrun[r] *= sc;
#pragma unroll
      for (int d = 0; d < 4; ++d) acc[d][r] *= sc;
      rs[r] = 0.f;
    }
#pragma unroll
    for (int sub = 0; sub < 4; ++sub) {
#pragma unroll
      for (int r = 0; r < 4; ++r) {
        const float p = __expf(sacc[sub][r] - mnew[r]);
        rs[r] += p;
        Pl[w][(lk * 4 + r) * 72 + sub * 16 + lr] = f2bf(p);
      }
    }
#pragma unroll
    for (int r = 0; r < 4; ++r) {
#pragma unroll
      for (int off = 1; off < 16; off <<= 1) rs[r] += __shfl_xor(rs[r], off, 64);
      lrun[r] += rs[r];
      mrun[r] = mnew[r];
    }

    // P writes must land before A-frag reads (same wave) — rule #18 fence
    asm volatile("s_waitcnt lgkmcnt(0)" ::: "memory");
    __builtin_amdgcn_sched_barrier(0);

    // --- O += P V : A from P_lds, B from swizzled Vt ---
    const bf16x8 ap0 = *(const bf16x8*)&Pl[w][lr * 72 + lk * 8];
    const bf16x8 ap1 = *(const bf16x8*)&Pl[w][lr * 72 + 32 + lk * 8];
#pragma unroll
    for (int d = 0; d < 4; ++d) {
      const int dd = d * 16 + lr;
      const int key = (dd ^ (dd >> 3)) & 7;
      const bf16x8 bv0 = *(const bf16x8*)&Vt[dd * 64 + ((lk ^ key) << 3)];
      const bf16x8 bv1 = *(const bf16x8*)&Vt[dd * 64 + (((4 + lk) ^ key) << 3)];
      acc[d] = __builtin_amdgcn_mfma_f32_16x16x32_bf16(ap0, bv0, acc[d], 0, 0, 0);
      acc[d] = __builtin_amdgcn_mfma_f32_16x16x32_bf16(ap1, bv1, acc[d], 0, 0, 0);
    }
  }

  // --- epilogue: ctx[q][h*64 + d] = O / l ---
#pragma unroll
  for (int d = 0; d < 4; ++d) {
#pragma unroll
    for (int r = 0; r < 4; ++r) {
      const int row = q0 + w * 16 + lk * 4 + r;
      const int col = h * 64 + d * 16 + lr;
      ctx[(size_t)row * 1024 + col] = f2bf(acc[d][r] / lrun[r]);
    }
  }
}

// ---------------------------------------------------------------------------
extern "C" void kernel_launch(void* const* d_in, const int* in_sizes, int n_in,
                              void* d_out, int out_size, void* d_ws, size_t ws_size,
                              hipStream_t stream) {
  const float* hid = (const float*)d_in[0];
  const float* Wq  = (const float*)d_in[1];
  const float* bq  = (const float*)d_in[2];
  const float* Wk  = (const float*)d_in[3];
  const float* bk  = (const float*)d_in[4];
  const float* Wv  = (const float*)d_in[5];
  const float* bv  = (const float*)d_in[6];
  const float* Wo  = (const float*)d_in[7];
  const float* bo  = (const float*)d_in[8];
  float* out = (float*)d_out;

  char* ws = (char*)d_ws;
  unsigned short* hb   = (unsigned short*)(ws);                 //  4 MB  hidden bf16
  unsigned short* Wcat = (unsigned short*)(ws + (4u  << 20));   //  6 MB  Wq|Wk|Wv bf16
  unsigned short* Wob  = (unsigned short*)(ws + (10u << 20));   //  2 MB  Wo bf16
  float*          bcat = (float*)         (ws + (12u << 20));   // 12 KB  bq/8|bk|bv
  unsigned short* QKV  = (unsigned short*)(ws + (13u << 20));   // 12 MB
  unsigned short* ctx  = (unsigned short*)(ws + (25u << 20));   //  4 MB

  const int HID4 = 2048 * 1024 / 4, W4 = 1024 * 1024 / 4;
  cvt_f32_bf16<<<HID4 / 256, 256, 0, stream>>>(hid, hb, HID4, 1.0f);
  cvt_f32_bf16<<<W4 / 256, 256, 0, stream>>>(Wq, Wcat,               W4, 0.125f); // fold 1/sqrt(64)
  cvt_f32_bf16<<<W4 / 256, 256, 0, stream>>>(Wk, Wcat + 1024 * 1024, W4, 1.0f);
  cvt_f32_bf16<<<W4 / 256, 256, 0, stream>>>(Wv, Wcat + 2048 * 1024, W4, 1.0f);
  cvt_f32_bf16<<<W4 / 256, 256, 0, stream>>>(Wo, Wob,                W4, 1.0f);
  build_bcat<<<12, 256, 0, stream>>>(bq, bk, bv, bcat);

  // QKV = hb @ Wcat^T + bcat   [2048 x 3072]
  gemm_bt<unsigned short><<<dim3(24, 16), 256, 0, stream>>>(
      hb, Wcat, bcat, QKV, 2048, 3072, 1024, 1024, 1024, 3072);

  // causal flash attention -> ctx [2048 x 1024] bf16
  attn_fwd<<<dim3(32, 16), 256, 0, stream>>>(QKV, ctx);

  // out = ctx @ Wo^T + bo   [2048 x 1024] fp32
  gemm_bt<float><<<dim3(8, 16), 256, 0, stream>>>(
      ctx, Wob, bo, out, 2048, 1024, 1024, 1024, 1024, 1024);
}

// Round 2
// 101.450 us; speedup vs baseline: 1.4223x; 1.4223x over previous
//
#include <hip/hip_runtime.h>

typedef __attribute__((ext_vector_type(8))) short bf16x8;   // 8 bf16 in 4 VGPRs
typedef __attribute__((ext_vector_type(4))) float f32x4;

#define GLDS16(SRC, DST) __builtin_amdgcn_global_load_lds( \
    (const __attribute__((address_space(1))) void*)(SRC),  \
    (__attribute__((address_space(3))) void*)(DST), 16, 0, 0)

__device__ __forceinline__ unsigned short f2bf(float f) {
  unsigned int u = __float_as_uint(f);
  u += 0x7FFFu + ((u >> 16) & 1u);       // RNE
  return (unsigned short)(u >> 16);
}

// ---------------- fused fp32 -> bf16 converts + bias concat -----------------
// segments (in float4 units): hidden | Wq(*0.125) | Wk | Wv | Wo | bcat(768)
__global__ void cvt_all(const float* __restrict__ hid,
                        const float* __restrict__ Wq, const float* __restrict__ Wk,
                        const float* __restrict__ Wv, const float* __restrict__ Wo,
                        const float* __restrict__ bq, const float* __restrict__ bk,
                        const float* __restrict__ bv,
                        unsigned short* __restrict__ hb, unsigned short* __restrict__ Wcat,
                        unsigned short* __restrict__ Wob, float* __restrict__ bcat) {
  const int H4 = 2048 * 1024 / 4, W4 = 1024 * 1024 / 4;
  int i = blockIdx.x * 256 + threadIdx.x;
  const float* src; unsigned short* dst; float scale = 1.0f; int j;
  if (i < H4)                { src = hid; dst = hb;                 j = i; }
  else if (i < H4 + W4)      { src = Wq;  dst = Wcat;               j = i - H4; scale = 0.125f; }
  else if (i < H4 + 2 * W4)  { src = Wk;  dst = Wcat + 1024 * 1024; j = i - H4 - W4; }
  else if (i < H4 + 3 * W4)  { src = Wv;  dst = Wcat + 2048 * 1024; j = i - H4 - 2 * W4; }
  else if (i < H4 + 4 * W4)  { src = Wo;  dst = Wob;                j = i - H4 - 3 * W4; }
  else {                                           // bias concat, fp32 out
    j = i - H4 - 4 * W4;                           // 0..767 float4s -> bcat[3072]
    int e = j * 4;
    const float* b = (e < 1024) ? bq : (e < 2048 ? bk + (-1024) : bv + (-2048));
    float4 v = *(const float4*)(b + e);
    if (e < 1024) { v.x *= 0.125f; v.y *= 0.125f; v.z *= 0.125f; v.w *= 0.125f; }
    ((float4*)bcat)[j] = v;
    return;
  }
  float4 v = ((const float4*)src)[j];
  ushort4 o;
  o.x = f2bf(v.x * scale); o.y = f2bf(v.y * scale);
  o.z = f2bf(v.z * scale); o.w = f2bf(v.w * scale);
  ((ushort4*)dst)[j] = o;
}

// ---------------- C = A * B^T + bias ; A[M,K] bf16, B[N,K] bf16 -----------
// m97 structure; BM=128: 4 waves 2x2, wave tile 64x64 (acc 4x4).
//                BM=64 : 4 waves 2x2, wave tile 32x64 (acc 2x4).
template <int BM, typename OutT>
__global__ __launch_bounds__(256) void gemm_bt(
    const unsigned short* __restrict__ A, const unsigned short* __restrict__ B,
    const float* __restrict__ bias, OutT* __restrict__ C,
    int M, int N, int K, int lda, int ldb, int ldc)
{
  constexpr int MREP = BM / 32;                 // 4 or 2
  __shared__ __align__(16) unsigned short As[2][BM * 32];
  __shared__ __align__(16) unsigned short Bs[2][128 * 32];
  const int t = threadIdx.x;
  const int lane = t & 63;
  const int w = t >> 6;
  const int wm = w >> 1, wn = w & 1;
  const int lr = lane & 15, lk = lane >> 4;
  const int tm = blockIdx.y * BM, tn = blockIdx.x * 128;

  f32x4 acc[MREP][4];
#pragma unroll
  for (int m = 0; m < MREP; ++m)
#pragma unroll
    for (int n = 0; n < 4; ++n) acc[m][n] = (f32x4){0.f, 0.f, 0.f, 0.f};

  const int ra0 = t >> 2;            // row = (t*8)/32
  const int ka0 = (t & 3) << 3;      // k within tile
  const int ra1 = 64 + (t >> 2);
  const int lds0 = (t & 192) * 8;            // wave-uniform base (elems)
  const int lds1 = (256 + (t & 192)) * 8;

  const int NT = K >> 5;
  GLDS16(A + (size_t)(tm + ra0) * lda + ka0, &As[0][lds0]);
  if constexpr (BM == 128) GLDS16(A + (size_t)(tm + ra1) * lda + ka0, &As[0][lds1]);
  GLDS16(B + (size_t)(tn + ra0) * ldb + ka0, &Bs[0][lds0]);
  GLDS16(B + (size_t)(tn + ra1) * ldb + ka0, &Bs[0][lds1]);
  __syncthreads();

  for (int kt = 0; kt < NT; ++kt) {
    const int cur = kt & 1, nxt = cur ^ 1;
    if (kt + 1 < NT) {
      const int k0 = (kt + 1) << 5;
      GLDS16(A + (size_t)(tm + ra0) * lda + k0 + ka0, &As[nxt][lds0]);
      if constexpr (BM == 128) GLDS16(A + (size_t)(tm + ra1) * lda + k0 + ka0, &As[nxt][lds1]);
      GLDS16(B + (size_t)(tn + ra0) * ldb + k0 + ka0, &Bs[nxt][lds0]);
      GLDS16(B + (size_t)(tn + ra1) * ldb + k0 + ka0, &Bs[nxt][lds1]);
    }
    bf16x8 af[MREP], bfv[4];
#pragma unroll
    for (int m = 0; m < MREP; ++m)
      af[m] = *(const bf16x8*)&As[cur][(wm * (BM / 2) + m * 16 + lr) * 32 + lk * 8];
#pragma unroll
    for (int n = 0; n < 4; ++n)
      bfv[n] = *(const bf16x8*)&Bs[cur][(wn * 64 + n * 16 + lr) * 32 + lk * 8];
#pragma unroll
    for (int m = 0; m < MREP; ++m)
#pragma unroll
      for (int n = 0; n < 4; ++n)
        acc[m][n] = __builtin_amdgcn_mfma_f32_16x16x32_bf16(af[m], bfv[n], acc[m][n], 0, 0, 0);
    __syncthreads();
  }

  // epilogue: C/D layout col=lane&15, row=(lane>>4)*4+reg  [m89]
#pragma unroll
  for (int m = 0; m < MREP; ++m) {
    const int row0 = tm + wm * (BM / 2) + m * 16 + lk * 4;
#pragma unroll
    for (int n = 0; n < 4; ++n) {
      const int col = tn + wn * 64 + n * 16 + lr;
      const float bb = bias ? bias[col] : 0.f;
#pragma unroll
      for (int r = 0; r < 4; ++r) {
        float v = acc[m][n][r] + bb;
        if constexpr (sizeof(OutT) == 2) {
          ((unsigned short*)C)[(size_t)(row0 + r) * ldc + col] = f2bf(v);
        } else {
          ((float*)C)[(size_t)(row0 + r) * ldc + col] = v;
        }
      }
    }
  }
}

// ---------------- causal flash attention (swapped QK^T, O^T PV) -------------
// QKV: [2048][3072] bf16, Q pre-scaled by 1/8. Block: 4 waves, 64 q-rows
// (wave w owns q = q0 + w*16 + lr). Swapped S^T = mfma(K, Q): lane holds
// S^T[kv][q=lane&15] -> softmax fully in-register (16 in-lane + 2 shfl_xor).
// PV as O^T = mfma(V^T, P^T): A from swizzled Vt, B = P^T via packed-u32 LDS.
__global__ __launch_bounds__(256) void attn_fwd(const unsigned short* __restrict__ QKV,
                                                unsigned short* __restrict__ ctx)
{
  __shared__ __align__(16) unsigned short Ks[64 * 64];
  __shared__ __align__(16) unsigned short Vt[64 * 64];
  __shared__ __align__(16) unsigned int   Pl[4][16 * 36];   // P^T packed u32, stride 36

  const int t = threadIdx.x;
  const int lane = t & 63, w = t >> 6;
  const int lr = lane & 15, lk = lane >> 4;
  const int h = blockIdx.y;
  // complementary pairing: blocks i and i+256 sum to 33 kv-tiles
  const int qt = (blockIdx.y < 8) ? (31 - (int)blockIdx.x) : (int)blockIdx.x;
  const int q0 = qt * 64;
  const size_t ldq = 3072;

  // Q as B-operand frags: lane holds Q[q0+w*16+lr][slice*32 + lk*8 + i]
  const unsigned short* qbase = QKV + (size_t)(q0 + w * 16 + lr) * ldq + h * 64;
  const bf16x8 qf0 = *(const bf16x8*)(qbase + lk * 8);
  const bf16x8 qf1 = *(const bf16x8*)(qbase + 32 + lk * 8);

  f32x4 acc[4];   // O^T: rows d = dsub*16 + lk*4 + r, col q = lr
#pragma unroll
  for (int d = 0; d < 4; ++d) acc[d] = (f32x4){0.f, 0.f, 0.f, 0.f};
  float mrun = -__builtin_inff(), lrun = 0.f;

  // staging geometry: thread t covers elems t*8 / (256+t)*8 of a 64x64 tile
  const int srow0 = t >> 3;           // kv row 0..31
  const int srow1 = 32 + (t >> 3);    // kv row 32..63
  const int sslot = t & 7;            // 16B slot within 128B row

  const unsigned short* kbase = QKV + 1024 + h * 64;
  const unsigned short* vbase = QKV + 2048 + h * 64;

  const int ntiles = qt + 1;
  for (int kt = 0; kt < ntiles; ++kt) {
    const int kv0 = kt * 64;
    __syncthreads();   // prior tile fully consumed before overwrite
    // --- stage K (linear LDS dest, inverse-swizzled global source) ---
    {
      const int c0 = (sslot ^ (srow0 & 7)) << 3;
      const int c1 = (sslot ^ (srow1 & 7)) << 3;
      GLDS16(kbase + (size_t)(kv0 + srow0) * ldq + c0, &Ks[(t & 192) * 8]);
      GLDS16(kbase + (size_t)(kv0 + srow1) * ldq + c1, &Ks[(256 + (t & 192)) * 8]);
    }
    // --- stage V transposed with slot swizzle ---
    {
      const bf16x8 v0 = *(const bf16x8*)(vbase + (size_t)(kv0 + srow0) * ldq + (sslot << 3));
      const bf16x8 v1 = *(const bf16x8*)(vbase + (size_t)(kv0 + srow1) * ldq + (sslot << 3));
      const int d0 = sslot << 3;
#pragma unroll
      for (int j = 0; j < 8; ++j) {
        const int d = d0 + j;
        const int key = (d ^ (d >> 3)) & 7;
        Vt[d * 64 + (((srow0 >> 3) ^ key) << 3) + (srow0 & 7)] = (unsigned short)v0[j];
        Vt[d * 64 + (((srow1 >> 3) ^ key) << 3) + (srow1 & 7)] = (unsigned short)v1[j];
      }
    }
    __syncthreads();   // staging visible (drains vmcnt+lgkm)

    // --- S^T = K Q^T : 4 kv-subtiles x 2 d-slices; D[kv][q], q = lr ---
    f32x4 sacc[4];
#pragma unroll
    for (int sub = 0; sub < 4; ++sub) {
      const int krow = sub * 16 + lr;
      const int sw = krow & 7;
      const bf16x8 kf0 = *(const bf16x8*)&Ks[krow * 64 + ((lk ^ sw) << 3)];
      const bf16x8 kf1 = *(const bf16x8*)&Ks[krow * 64 + (((4 + lk) ^ sw) << 3)];
      f32x4 s = (f32x4){0.f, 0.f, 0.f, 0.f};
      s = __builtin_amdgcn_mfma_f32_16x16x32_bf16(kf0, qf0, s, 0, 0, 0);
      s = __builtin_amdgcn_mfma_f32_16x16x32_bf16(kf1, qf1, s, 0, 0, 0);
      sacc[sub] = s;
    }

    // --- causal mask (diagonal tile only): kv_local > q_local -> -inf ---
    if (kt == ntiles - 1) {
      const int qg = w * 16 + lr;
#pragma unroll
      for (int sub = 0; sub < 4; ++sub) {
#pragma unroll
        for (int r = 0; r < 4; ++r)
          if (sub * 16 + lk * 4 + r > qg) sacc[sub][r] = -__builtin_inff();
      }
    }

    // --- online softmax, fully in-register (q = lr is lane-local) ---
    float pm = -__builtin_inff();
#pragma unroll
    for (int sub = 0; sub < 4; ++sub)
#pragma unroll
      for (int r = 0; r < 4; ++r) pm = fmaxf(pm, sacc[sub][r]);
    pm = fmaxf(pm, __shfl_xor(pm, 16, 64));
    pm = fmaxf(pm, __shfl_xor(pm, 32, 64));
    const float mnew = fmaxf(mrun, pm);
    const float sc = __expf(mrun - mnew);   // 0 on first tile
    lrun *= sc;
#pragma unroll
    for (int d = 0; d < 4; ++d) acc[d] *= sc;
    float p[4][4]; float rs = 0.f;
#pragma unroll
    for (int sub = 0; sub < 4; ++sub)
#pragma unroll
      for (int r = 0; r < 4; ++r) { p[sub][r] = __expf(sacc[sub][r] - mnew); rs += p[sub][r]; }
    rs += __shfl_xor(rs, 16, 64);
    rs += __shfl_xor(rs, 32, 64);
    lrun += rs;
    mrun = mnew;

    // --- pack P^T to bf16 pairs, write per-wave LDS (2-way conflicts max) ---
    unsigned int* prow = &Pl[w][lr * 36];
#pragma unroll
    for (int sub = 0; sub < 4; ++sub) {
#pragma unroll
      for (int j = 0; j < 2; ++j) {
        unsigned int pk;
        asm("v_cvt_pk_bf16_f32 %0, %1, %2" : "=v"(pk) : "v"(p[sub][2 * j]), "v"(p[sub][2 * j + 1]));
        prow[sub * 8 + lk * 2 + j] = pk;
      }
    }
    asm volatile("s_waitcnt lgkmcnt(0)" ::: "memory");   // rule #18 fence
    __builtin_amdgcn_sched_barrier(0);

    // --- O^T += V^T P^T : A from swizzled Vt, B = P^T (16B-aligned b128) ---
    const bf16x8 pb0 = *(const bf16x8*)&Pl[w][lr * 36 + lk * 4];
    const bf16x8 pb1 = *(const bf16x8*)&Pl[w][lr * 36 + 16 + lk * 4];
#pragma unroll
    for (int dsub = 0; dsub < 4; ++dsub) {
      const int dd = dsub * 16 + lr;
      const int key = (dd ^ (dd >> 3)) & 7;
      const bf16x8 bv0 = *(const bf16x8*)&Vt[dd * 64 + ((lk ^ key) << 3)];
      const bf16x8 bv1 = *(const bf16x8*)&Vt[dd * 64 + (((4 + lk) ^ key) << 3)];
      acc[dsub] = __builtin_amdgcn_mfma_f32_16x16x32_bf16(bv0, pb0, acc[dsub], 0, 0, 0);
      acc[dsub] = __builtin_amdgcn_mfma_f32_16x16x32_bf16(bv1, pb1, acc[dsub], 0, 0, 0);
    }
  }

  // --- epilogue: ctx[q][h*64 + d] = O^T[d][q] / l ; 8B packed stores ---
  const float inv = 1.0f / lrun;
#pragma unroll
  for (int dsub = 0; dsub < 4; ++dsub) {
    ushort4 o;
    o.x = f2bf(acc[dsub][0] * inv);
    o.y = f2bf(acc[dsub][1] * inv);
    o.z = f2bf(acc[dsub][2] * inv);
    o.w = f2bf(acc[dsub][3] * inv);
    *(ushort4*)&ctx[(size_t)(q0 + w * 16 + lr) * 1024 + h * 64 + dsub * 16 + lk * 4] = o;
  }
}

// ---------------------------------------------------------------------------
extern "C" void kernel_launch(void* const* d_in, const int* in_sizes, int n_in,
                              void* d_out, int out_size, void* d_ws, size_t ws_size,
                              hipStream_t stream) {
  const float* hid = (const float*)d_in[0];
  const float* Wq  = (const float*)d_in[1];
  const float* bq  = (const float*)d_in[2];
  const float* Wk  = (const float*)d_in[3];
  const float* bk  = (const float*)d_in[4];
  const float* Wv  = (const float*)d_in[5];
  const float* bv  = (const float*)d_in[6];
  const float* Wo  = (const float*)d_in[7];
  const float* bo  = (const float*)d_in[8];
  float* out = (float*)d_out;

  char* ws = (char*)d_ws;
  unsigned short* hb   = (unsigned short*)(ws);                 //  4 MB  hidden bf16
  unsigned short* Wcat = (unsigned short*)(ws + (4u  << 20));   //  6 MB  Wq|Wk|Wv bf16
  unsigned short* Wob  = (unsigned short*)(ws + (10u << 20));   //  2 MB  Wo bf16
  float*          bcat = (float*)         (ws + (12u << 20));   // 12 KB  bq/8|bk|bv
  unsigned short* QKV  = (unsigned short*)(ws + (13u << 20));   // 12 MB
  unsigned short* ctx  = (unsigned short*)(ws + (25u << 20));   //  4 MB

  // fused converts: hidden, Wq(*1/8), Wk, Wv, Wo, bias concat  (6147 blocks)
  cvt_all<<<6147, 256, 0, stream>>>(hid, Wq, Wk, Wv, Wo, bq, bk, bv,
                                    hb, Wcat, Wob, bcat);

  // QKV = hb @ Wcat^T + bcat   [2048 x 3072]
  gemm_bt<128, unsigned short><<<dim3(24, 16), 256, 0, stream>>>(
      hb, Wcat, bcat, QKV, 2048, 3072, 1024, 1024, 1024, 3072);

  // causal flash attention -> ctx [2048 x 1024] bf16
  attn_fwd<<<dim3(32, 16), 256, 0, stream>>>(QKV, ctx);

  // out = ctx @ Wo^T + bo   [2048 x 1024] fp32  (BM=64 -> 256 blocks)
  gemm_bt<64, float><<<dim3(8, 32), 256, 0, stream>>>(
      ctx, Wob, bo, out, 2048, 1024, 1024, 1024, 1024, 1024);
}